// Round 2
// baseline (21142.677 us; speedup 1.0000x reference)
//
#include <hip/hip_runtime.h>
#include <hip/hip_bf16.h>

// LSTM: B=64, D=32, H=512, T=1024. gates = [h,x] @ [W_hh;W_ih]^T + b_ih + b_hh
// Persistent-ish dataflow design:
//   grid = 256 blocks (4 batch-groups of 16  x  64 hidden-slices of 8 units),
//   128 threads (2 waves; wave w owns 4 hidden units -> 16 gate rows).
//   W_hi in VGPRs, W_lo in LDS (stationary). h exchanged per step through L3
//   with step-indexed flags (relaxed agent atomics) + acquire/release fences.
//   bf16 hi/lo 3-term MFMA => ~2^-17 matmul error.
// 256 blocks @ 1 block/CU (35KB LDS, <512 VGPR at 1 wave/EU) => co-resident.

typedef unsigned short ushort_t;
typedef unsigned int   uint_t;
typedef __attribute__((ext_vector_type(8))) short bf16x8;
typedef __attribute__((ext_vector_type(4))) float f32x4;

#define T_STEPS 1024
#define HID     512
#define KDIM    544   // 512 h + 32 x
#define NBLK    256   // 4 groups * 64 slices
#define NTHR    128

__device__ inline ushort_t f2bf(float x) {
    __hip_bfloat16 h = __float2bfloat16(x);
    return *(ushort_t*)&h;
}
__device__ inline float bf2f(ushort_t u) {
    __hip_bfloat16 h = *(__hip_bfloat16*)&u;
    return __bfloat162float(h);
}

__device__ inline f32x4 MFMA(bf16x8 a, bf16x8 b, f32x4 c) {
    return __builtin_amdgcn_mfma_f32_16x16x32_bf16(a, b, c, 0, 0, 0);
}

// is_tanh: tanh(v) = (1-e)/(1+e), e=2^(-2.885*v); else sigmoid(v)=1/(1+e), e=2^(-1.4427*v)
__device__ inline float act_gate(float v, int is_tanh) {
    float vc = fminf(fmaxf(v, -43.f), 43.f);
    float kk = is_tanh ? -2.88539008f : -1.44269504f;
    float e  = __builtin_exp2f(vc * kk);
    float num = is_tanh ? (1.f - e) : 1.f;
    return num * __builtin_amdgcn_rcpf(1.f + e);
}

__device__ inline float sel4(int i, float a, float b, float c, float d) {
    return (i == 0) ? a : (i == 1) ? b : (i == 2) ? c : d;
}

// ---------- prep kernels ----------

__global__ void k_init(uint_t* flags, uint_t* hr_hi32, uint_t* hr_lo32,
                       float* out, const float* conv_b) {
    int i = blockIdx.x * 256 + threadIdx.x;     // grid 1024x256 = 262144
    flags[i] = 0;                                // 1024*4*64 u32 = exactly 262144
    if (i < 32768) { hr_hi32[i] = 0; hr_lo32[i] = 0; }  // whole h ring (both slots)
    if (i < 65536) out[i] = conv_b[0];
}

__global__ void k_wcat(const float* __restrict__ wih, const float* __restrict__ whh,
                       ushort_t* __restrict__ wh, ushort_t* __restrict__ wl) {
    int r = blockIdx.x;                          // 2048 gate rows
    for (int k = threadIdx.x; k < KDIM; k += 256) {
        float w = (k < 512) ? whh[r * 512 + k] : wih[r * 32 + (k - 512)];
        ushort_t hh = f2bf(w);
        ushort_t ll = f2bf(w - bf2f(hh));
        wh[r * KDIM + k] = hh;
        wl[r * KDIM + k] = ll;
    }
}

// input (B=64, D=32, T=1024) fp32 -> xbuf[t][b][d] bf16 hi/lo
__global__ void k_xbuf(const float* __restrict__ in,
                       ushort_t* __restrict__ xh, ushort_t* __restrict__ xl) {
    __shared__ float tile[64][65];
    int bp = blockIdx.x >> 4;                    // batch pair 0..31
    int tt = blockIdx.x & 15;                    // t tile 0..15
    int t0 = tt * 64;
    int wv = threadIdx.x >> 6, l = threadIdx.x & 63;
    for (int r = wv * 16; r < wv * 16 + 16; r++) {
        int b = bp * 2 + (r >> 5), d = r & 31;
        tile[r][l] = in[(b * 32 + d) * 1024 + t0 + l];
    }
    __syncthreads();
    for (int i = 0; i < 16; i++) {
        int tl = wv * 16 + i;
        float v = tile[l][tl];
        ushort_t hh = f2bf(v);
        ushort_t ll = f2bf(v - bf2f(hh));
        int o = (t0 + tl) * 2048 + bp * 64 + l;  // = t*64*32 + b*32 + d
        xh[o] = hh;
        xl[o] = ll;
    }
}

// ---------- main recurrent kernel ----------

__global__ __launch_bounds__(NTHR, 1) void k_lstm(
    const ushort_t* __restrict__ wh, const ushort_t* __restrict__ wlo,
    const ushort_t* __restrict__ xh, const ushort_t* __restrict__ xl,
    ushort_t* hr_hi, ushort_t* hr_lo, uint_t* flags,
    const float* __restrict__ bih, const float* __restrict__ bhh,
    const float* __restrict__ convw, float* __restrict__ out)
{
    const int tid = threadIdx.x;
    const int w   = tid >> 6;          // wave 0/1 (unit nibble)
    const int l   = tid & 63;
    const int g   = blockIdx.x >> 6;   // batch group 0..3
    const int s   = blockIdx.x & 63;   // hidden slice 0..63
    const int n   = l & 15;            // B-tile row within wave
    const int q   = l >> 4;            // quad
    const int gtn = n >> 2;            // gate 0..3 (i,f,g,o)
    const int u   = n & 3;             // unit within wave
    const int j   = s * 8 + w * 4 + u; // hidden unit 0..511
    const int row = gtn * HID + j;     // gate row 0..2047
    const int b0  = g * 16;

    __shared__ ushort_t blo[32][552];  // W_lo slice, padded stride (2-way conflict only)
    __shared__ float predsh[2][16];

    // stage W_lo to LDS: 32 rows x 544, 8-elem (16B) chunks
    for (int e = tid; e < 32 * 68; e += NTHR) {
        int rl = e / 68, ch = e - rl * 68;
        int gg = (rl >> 2) & 3, uu = rl & 3, ww = (rl >> 4) & 1;
        int rr = gg * HID + s * 8 + ww * 4 + uu;
        *(bf16x8*)&blo[rl][ch * 8] = *(const bf16x8*)(wlo + rr * KDIM + ch * 8);
    }

    // W_hi fragments in registers: 17 K-chunks
    bf16x8 Bh[17];
    #pragma unroll
    for (int c = 0; c < 17; c++)
        Bh[c] = *(const bf16x8*)(wh + row * KDIM + c * 32 + q * 8);

    const float bias = bih[row] + bhh[row];
    const float cw   = convw[j];
    float cst[4] = {0.f, 0.f, 0.f, 0.f};

    __syncthreads();
    const int rl16 = w * 16 + n;

    for (int t = 0; t < T_STEPS; t++) {
        if (t > 0) {
            if (w == 0) {
                const uint_t* fl = flags + (t - 1) * 256 + g * 64;
                for (;;) {
                    uint_t f = __hip_atomic_load(fl + l, __ATOMIC_RELAXED,
                                                 __HIP_MEMORY_SCOPE_AGENT);
                    if (__all(f != 0)) break;
                }
            }
            __syncthreads();
            __builtin_amdgcn_fence(__ATOMIC_ACQUIRE, "agent");
        }

        // A fragments: h from ring slot t&1 (rows m=n), x from xbuf[t]
        const ushort_t* ph = hr_hi + (((t & 1) * 4 + g) * 16 + n) * HID;
        const ushort_t* pl = hr_lo + (((t & 1) * 4 + g) * 16 + n) * HID;
        bf16x8 Ah[17], Al[17];
        #pragma unroll
        for (int c = 0; c < 16; c++) {
            Ah[c] = *(const bf16x8*)(ph + c * 32 + q * 8);
            Al[c] = *(const bf16x8*)(pl + c * 32 + q * 8);
        }
        {
            int xo = (t * 64 + b0 + n) * 32 + q * 8;
            Ah[16] = *(const bf16x8*)(xh + xo);
            Al[16] = *(const bf16x8*)(xl + xo);
        }

        f32x4 a0 = {0,0,0,0}, a1 = {0,0,0,0}, a2 = {0,0,0,0},
              a3 = {0,0,0,0}, a4 = {0,0,0,0}, a5 = {0,0,0,0};
        #pragma unroll
        for (int c = 0; c < 17; c++) {
            bf16x8 bl_ = *(const bf16x8*)&blo[rl16][c * 32 + q * 8];
            if (c & 1) {
                a1 = MFMA(Ah[c], Bh[c], a1);
                a3 = MFMA(Ah[c], bl_,   a3);
                a5 = MFMA(Al[c], Bh[c], a5);
            } else {
                a0 = MFMA(Ah[c], Bh[c], a0);
                a2 = MFMA(Ah[c], bl_,   a2);
                a4 = MFMA(Al[c], Bh[c], a4);
            }
        }
        f32x4 D = (a0 + a1) + (a2 + a3) + (a4 + a5);

        // epilogue: lane holds gate row n for batches m=q*4+r
        float hv[4], pr[4];
        #pragma unroll
        for (int r = 0; r < 4; r++) {
            float v   = D[r] + bias;
            float act = act_gate(v, gtn == 2);
            float v4  = __shfl_xor(act, 4);
            float v8  = __shfl_xor(act, 8);
            float v12 = __shfl_xor(v4, 8);
            // gate G lives at arr[gtn ^ G]; arr = {act, v4, v8, v12}
            float iv = sel4(gtn,     act, v4, v8, v12);
            float fv = sel4(gtn ^ 1, act, v4, v8, v12);
            float gv = sel4(gtn ^ 2, act, v4, v8, v12);
            float ov = sel4(gtn ^ 3, act, v4, v8, v12);
            float cc = fv * cst[r] + iv * gv;
            cst[r] = cc;
            float th = act_gate(cc, 1);
            float h  = ov * th;
            hv[r] = h;
            pr[r] = cw * h;
        }
        // sum projection partial over this wave's 4 units (lane bits 0..1)
        #pragma unroll
        for (int r = 0; r < 4; r++) {
            pr[r] += __shfl_xor(pr[r], 1);
            pr[r] += __shfl_xor(pr[r], 2);
        }
        // write h_t (hi/lo) to ring slot (t+1)&1  [gate-0 lanes own units]
        if (gtn == 0) {
            ushort_t* dh = hr_hi + ((((t + 1) & 1) * 4 + g) * 16) * HID;
            ushort_t* dl = hr_lo + ((((t + 1) & 1) * 4 + g) * 16) * HID;
            #pragma unroll
            for (int r = 0; r < 4; r++) {
                int m2 = q * 4 + r;
                float h = hv[r];
                ushort_t hh = f2bf(h);
                ushort_t ll = f2bf(h - bf2f(hh));
                dh[m2 * HID + j] = hh;
                dl[m2 * HID + j] = ll;
            }
        }
        if (n == 0) {
            #pragma unroll
            for (int r = 0; r < 4; r++) predsh[w][q * 4 + r] = pr[r];
        }
        __threadfence();          // release h stores device-wide
        __syncthreads();
        if (tid < 16) {
            float tot = predsh[0][tid] + predsh[1][tid];
            atomicAdd(out + (b0 + tid) * 1024 + t, tot);
        }
        __syncthreads();          // predsh read done; order flag after everything
        if (tid == 0)
            __hip_atomic_store(flags + t * 256 + g * 64 + s, 1u,
                               __ATOMIC_RELAXED, __HIP_MEMORY_SCOPE_AGENT);
    }
}

extern "C" void kernel_launch(void* const* d_in, const int* in_sizes, int n_in,
                              void* d_out, int out_size, void* d_ws, size_t ws_size,
                              hipStream_t stream) {
    const float* in  = (const float*)d_in[0];
    const float* Wih = (const float*)d_in[1];
    const float* Whh = (const float*)d_in[2];
    const float* bih = (const float*)d_in[3];
    const float* bhh = (const float*)d_in[4];
    const float* cvw = (const float*)d_in[5];
    const float* cvb = (const float*)d_in[6];
    float* out = (float*)d_out;

    char* ws = (char*)d_ws;
    ushort_t* wh = (ushort_t*)ws; ws += (size_t)2048 * KDIM * 2;   // 2,228,224
    ushort_t* wl = (ushort_t*)ws; ws += (size_t)2048 * KDIM * 2;
    ushort_t* xh = (ushort_t*)ws; ws += (size_t)1024 * 64 * 32 * 2; // 4,194,304
    ushort_t* xl = (ushort_t*)ws; ws += (size_t)1024 * 64 * 32 * 2;
    ushort_t* hh = (ushort_t*)ws; ws += (size_t)2 * 4 * 16 * HID * 2; // 131,072
    ushort_t* hl = (ushort_t*)ws; ws += (size_t)2 * 4 * 16 * HID * 2;
    uint_t*   fl = (uint_t*)ws;   ws += (size_t)T_STEPS * 256 * 4;    // 1,048,576
    // total ~13.5 MB of ws

    k_init<<<1024, 256, 0, stream>>>(fl, (uint_t*)hh, (uint_t*)hl, out, cvb);
    k_wcat<<<2048, 256, 0, stream>>>(Wih, Whh, wh, wl);
    k_xbuf<<<512, 256, 0, stream>>>(in, xh, xl);
    k_lstm<<<NBLK, NTHR, 0, stream>>>(wh, wl, xh, xl, hh, hl, fl,
                                      bih, bhh, cvw, out);
}

// Round 3
// 11533.410 us; speedup vs baseline: 1.8332x; 1.8332x over previous
//
#include <hip/hip_runtime.h>
#include <hip/hip_bf16.h>

// LSTM: B=64, D=32, H=512, T=1024. gates = [h,x] @ [W_hh;W_ih]^T + b_ih + b_hh
// Round 3: 128 blocks (4 batch-groups x 32 slices of 16 units), 256 threads
// (4 waves; wave w owns units w*4..w*4+3 -> 16 gate rows). W_hi in VGPRs,
// W_lo in LDS. h exchanged per step via L3 with step-indexed flags.
// Sync cost reduction vs R2: wave0-only acquire inv, tid0-only release wb
// (256 cache-maint ops/step vs 1024), per-step out atomicAdd replaced by
// nontemporal partial stores + k_reduce epilogue kernel.

typedef unsigned short ushort_t;
typedef unsigned int   uint_t;
typedef __attribute__((ext_vector_type(8))) short bf16x8;
typedef __attribute__((ext_vector_type(4))) float f32x4;

#define T_STEPS 1024
#define HID     512
#define KDIM    544   // 512 h + 32 x
#define NBLK    128   // 4 groups * 32 slices
#define NTHR    256

__device__ inline ushort_t f2bf(float x) {
    __hip_bfloat16 h = __float2bfloat16(x);
    return *(ushort_t*)&h;
}
__device__ inline float bf2f(ushort_t u) {
    __hip_bfloat16 h = *(__hip_bfloat16*)&u;
    return __bfloat162float(h);
}

__device__ inline f32x4 MFMA(bf16x8 a, bf16x8 b, f32x4 c) {
    return __builtin_amdgcn_mfma_f32_16x16x32_bf16(a, b, c, 0, 0, 0);
}

// is_tanh: tanh(v)=(1-e)/(1+e), e=2^(-2.885*v); sigmoid(v)=1/(1+e), e=2^(-1.4427*v)
__device__ inline float act_gate(float v, int is_tanh) {
    float vc = fminf(fmaxf(v, -43.f), 43.f);
    float kk = is_tanh ? -2.88539008f : -1.44269504f;
    float e  = __builtin_exp2f(vc * kk);
    float num = is_tanh ? (1.f - e) : 1.f;
    return num * __builtin_amdgcn_rcpf(1.f + e);
}

__device__ inline float sel4(int i, float a, float b, float c, float d) {
    return (i == 0) ? a : (i == 1) ? b : (i == 2) ? c : d;
}

// ---------- prep kernels ----------

__global__ void k_init(uint_t* flags, uint_t* hr_hi32, uint_t* hr_lo32) {
    int i = blockIdx.x * 256 + threadIdx.x;     // grid 512x256 = 131072
    flags[i] = 0;                                // 1024*128 u32 = exactly 131072
    if (i < 32768) { hr_hi32[i] = 0; hr_lo32[i] = 0; }  // h ring, both slots
}

__global__ void k_wcat(const float* __restrict__ wih, const float* __restrict__ whh,
                       ushort_t* __restrict__ wh, ushort_t* __restrict__ wl) {
    int r = blockIdx.x;                          // 2048 gate rows
    for (int k = threadIdx.x; k < KDIM; k += 256) {
        float w = (k < 512) ? whh[r * 512 + k] : wih[r * 32 + (k - 512)];
        ushort_t hh = f2bf(w);
        ushort_t ll = f2bf(w - bf2f(hh));
        wh[r * KDIM + k] = hh;
        wl[r * KDIM + k] = ll;
    }
}

// input (B=64, D=32, T=1024) fp32 -> xbuf[t][b][d] bf16 hi/lo
__global__ void k_xbuf(const float* __restrict__ in,
                       ushort_t* __restrict__ xh, ushort_t* __restrict__ xl) {
    __shared__ float tile[64][65];
    int bp = blockIdx.x >> 4;                    // batch pair 0..31
    int tt = blockIdx.x & 15;                    // t tile 0..15
    int t0 = tt * 64;
    int wv = threadIdx.x >> 6, l = threadIdx.x & 63;
    for (int r = wv * 16; r < wv * 16 + 16; r++) {
        int b = bp * 2 + (r >> 5), d = r & 31;
        tile[r][l] = in[(b * 32 + d) * 1024 + t0 + l];
    }
    __syncthreads();
    for (int i = 0; i < 16; i++) {
        int tl = wv * 16 + i;
        float v = tile[l][tl];
        ushort_t hh = f2bf(v);
        ushort_t ll = f2bf(v - bf2f(hh));
        int o = (t0 + tl) * 2048 + bp * 64 + l;  // = t*64*32 + b*32 + d
        xh[o] = hh;
        xl[o] = ll;
    }
}

// final: out[b][t] = conv_b + sum_s part[b][t][s]
__global__ void k_reduce(const float* __restrict__ part, float* __restrict__ out,
                         const float* __restrict__ cvb) {
    int idx = blockIdx.x * 256 + threadIdx.x;    // 65536 = (b,t) pairs
    const float* p = part + (size_t)idx * 32;
    float s = 0.f;
    #pragma unroll
    for (int k = 0; k < 8; k++) {
        f32x4 v = *(const f32x4*)(p + k * 4);
        s += (v[0] + v[1]) + (v[2] + v[3]);
    }
    out[idx] = s + cvb[0];
}

// ---------- main recurrent kernel ----------

__global__ __launch_bounds__(NTHR, 1) void k_lstm(
    const ushort_t* __restrict__ wh, const ushort_t* __restrict__ wlo,
    const ushort_t* __restrict__ xh, const ushort_t* __restrict__ xl,
    ushort_t* hr_hi, ushort_t* hr_lo, uint_t* flags,
    const float* __restrict__ bih, const float* __restrict__ bhh,
    const float* __restrict__ convw, float* __restrict__ part)
{
    const int tid = threadIdx.x;
    const int w   = tid >> 6;          // wave 0..3 (unit nibble)
    const int l   = tid & 63;
    const int g   = blockIdx.x >> 5;   // batch group 0..3
    const int s   = blockIdx.x & 31;   // hidden slice 0..31 (16 units each)
    const int n   = l & 15;            // B-tile row within wave
    const int q   = l >> 4;            // quad
    const int gtn = n >> 2;            // gate 0..3 (i,f,g,o)
    const int u   = n & 3;             // unit within wave
    const int j   = s * 16 + w * 4 + u;// hidden unit 0..511
    const int row = gtn * HID + j;     // gate row 0..2047
    const int b0  = g * 16;

    __shared__ ushort_t blo[64][552];  // W_lo slice, padded stride
    __shared__ float predsh[4][16];

    // stage W_lo to LDS: 64 rows x 544, 8-elem (16B) chunks
    for (int e = tid; e < 64 * 68; e += NTHR) {
        int rl = e / 68, ch = e - rl * 68;
        int ww = rl >> 4, nn = rl & 15;
        int gg = nn >> 2, uu = nn & 3;
        int rr = gg * HID + s * 16 + ww * 4 + uu;
        *(bf16x8*)&blo[rl][ch * 8] = *(const bf16x8*)(wlo + rr * KDIM + ch * 8);
    }

    // W_hi fragments in registers: 17 K-chunks
    bf16x8 Bh[17];
    #pragma unroll
    for (int c = 0; c < 17; c++)
        Bh[c] = *(const bf16x8*)(wh + row * KDIM + c * 32 + q * 8);

    const float bias = bih[row] + bhh[row];
    const float cw   = convw[j];
    float cst[4] = {0.f, 0.f, 0.f, 0.f};

    __syncthreads();
    const int rl16 = w * 16 + n;

    for (int t = 0; t < T_STEPS; t++) {
        bf16x8 Ah[17], Al[17];
        // x fragment: no dependence on flags -> prefetch into regs before poll
        {
            int xo = (t * 64 + b0 + n) * 32 + q * 8;
            Ah[16] = *(const bf16x8*)(xh + xo);
            Al[16] = *(const bf16x8*)(xl + xo);
        }

        if (t > 0) {
            if (w == 0) {
                const uint_t* flp = flags + (t - 1) * 128 + g * 32;
                const uint_t* my  = flp + (l & 31);
                for (;;) {
                    uint_t f = __hip_atomic_load(my, __ATOMIC_RELAXED,
                                                 __HIP_MEMORY_SCOPE_AGENT);
                    if (__all(f != 0)) break;
                }
                // inv is vmcnt-tracked; pre-barrier vmcnt(0) drains it, so
                // waves 1..3's loads after the barrier see fresh lines.
                __builtin_amdgcn_fence(__ATOMIC_ACQUIRE, "agent");
            }
            __syncthreads();
        }

        // h fragments from ring slot t&1 (rows m=n)
        const ushort_t* ph = hr_hi + (((t & 1) * 4 + g) * 16 + n) * HID;
        const ushort_t* pl = hr_lo + (((t & 1) * 4 + g) * 16 + n) * HID;
        #pragma unroll
        for (int c = 0; c < 16; c++) {
            Ah[c] = *(const bf16x8*)(ph + c * 32 + q * 8);
            Al[c] = *(const bf16x8*)(pl + c * 32 + q * 8);
        }

        f32x4 a0 = {0,0,0,0}, a1 = {0,0,0,0}, a2 = {0,0,0,0},
              a3 = {0,0,0,0}, a4 = {0,0,0,0}, a5 = {0,0,0,0};
        #pragma unroll
        for (int c = 0; c < 17; c++) {
            bf16x8 bl_ = *(const bf16x8*)&blo[rl16][c * 32 + q * 8];
            if (c & 1) {
                a1 = MFMA(Ah[c], Bh[c], a1);
                a3 = MFMA(Ah[c], bl_,   a3);
                a5 = MFMA(Al[c], Bh[c], a5);
            } else {
                a0 = MFMA(Ah[c], Bh[c], a0);
                a2 = MFMA(Ah[c], bl_,   a2);
                a4 = MFMA(Al[c], Bh[c], a4);
            }
        }
        f32x4 D = (a0 + a1) + (a2 + a3) + (a4 + a5);

        // epilogue: lane holds gate row n for batches m=q*4+r
        float hv[4], pr[4];
        #pragma unroll
        for (int r = 0; r < 4; r++) {
            float v   = D[r] + bias;
            float act = act_gate(v, gtn == 2);
            float v4  = __shfl_xor(act, 4);
            float v8  = __shfl_xor(act, 8);
            float v12 = __shfl_xor(v4, 8);
            // gate G lives at arr[gtn ^ G]; arr = {act, v4, v8, v12}
            float iv = sel4(gtn,     act, v4, v8, v12);
            float fv = sel4(gtn ^ 1, act, v4, v8, v12);
            float gv = sel4(gtn ^ 2, act, v4, v8, v12);
            float ov = sel4(gtn ^ 3, act, v4, v8, v12);
            float cc = fv * cst[r] + iv * gv;
            cst[r] = cc;
            float th = act_gate(cc, 1);
            float h  = ov * th;
            hv[r] = h;
            pr[r] = cw * h;
        }
        // sum projection partial over this wave's 4 units (lane bits 0..1)
        #pragma unroll
        for (int r = 0; r < 4; r++) {
            pr[r] += __shfl_xor(pr[r], 1);
            pr[r] += __shfl_xor(pr[r], 2);
        }
        // write h_t (hi/lo) to ring slot (t+1)&1  [gate-0 lanes own units]
        if (gtn == 0) {
            ushort_t* dh = hr_hi + ((((t + 1) & 1) * 4 + g) * 16) * HID;
            ushort_t* dl = hr_lo + ((((t + 1) & 1) * 4 + g) * 16) * HID;
            #pragma unroll
            for (int r = 0; r < 4; r++) {
                int m2 = q * 4 + r;
                float h = hv[r];
                ushort_t hh = f2bf(h);
                ushort_t ll = f2bf(h - bf2f(hh));
                __builtin_nontemporal_store(hh, dh + m2 * HID + j);
                __builtin_nontemporal_store(ll, dl + m2 * HID + j);
            }
        }
        if (n == 0) {
            #pragma unroll
            for (int r = 0; r < 4; r++) predsh[w][q * 4 + r] = pr[r];
        }
        __syncthreads();   // drains all waves' h stores (pre-barrier vmcnt(0))
        if (tid == 0) {
            __builtin_amdgcn_fence(__ATOMIC_RELEASE, "agent");
            __hip_atomic_store(flags + t * 128 + g * 32 + s, 1u,
                               __ATOMIC_RELAXED, __HIP_MEMORY_SCOPE_AGENT);
        }
        if (tid < 16) {    // projection partial -> global, reduced after kernel
            float tot = (predsh[0][tid] + predsh[1][tid]) +
                        (predsh[2][tid] + predsh[3][tid]);
            __builtin_nontemporal_store(tot,
                part + (size_t)((b0 + tid) * 1024 + t) * 32 + s);
        }
        // next iteration's predsh writes are gated by its poll+__syncthreads,
        // which orders them after this iteration's predsh reads.
    }
}

extern "C" void kernel_launch(void* const* d_in, const int* in_sizes, int n_in,
                              void* d_out, int out_size, void* d_ws, size_t ws_size,
                              hipStream_t stream) {
    const float* in  = (const float*)d_in[0];
    const float* Wih = (const float*)d_in[1];
    const float* Whh = (const float*)d_in[2];
    const float* bih = (const float*)d_in[3];
    const float* bhh = (const float*)d_in[4];
    const float* cvw = (const float*)d_in[5];
    const float* cvb = (const float*)d_in[6];
    float* out = (float*)d_out;

    char* ws = (char*)d_ws;
    ushort_t* wh = (ushort_t*)ws; ws += (size_t)2048 * KDIM * 2;      // 2,228,224
    ushort_t* wl = (ushort_t*)ws; ws += (size_t)2048 * KDIM * 2;
    ushort_t* xh = (ushort_t*)ws; ws += (size_t)1024 * 64 * 32 * 2;   // 4,194,304
    ushort_t* xl = (ushort_t*)ws; ws += (size_t)1024 * 64 * 32 * 2;
    ushort_t* hh = (ushort_t*)ws; ws += (size_t)2 * 4 * 16 * HID * 2; // 131,072
    ushort_t* hl = (ushort_t*)ws; ws += (size_t)2 * 4 * 16 * HID * 2;
    uint_t*   fl = (uint_t*)ws;   ws += (size_t)T_STEPS * 128 * 4;    // 524,288
    float*    pp = (float*)ws;    ws += (size_t)64 * 1024 * 32 * 4;   // 8,388,608
    // total ~22.2 MB of ws

    k_init<<<512, 256, 0, stream>>>(fl, (uint_t*)hh, (uint_t*)hl);
    k_wcat<<<2048, 256, 0, stream>>>(Wih, Whh, wh, wl);
    k_xbuf<<<512, 256, 0, stream>>>(in, xh, xl);
    k_lstm<<<NBLK, NTHR, 0, stream>>>(wh, wl, xh, xl, hh, hl, fl,
                                      bih, bhh, cvw, pp);
    k_reduce<<<256, 256, 0, stream>>>(pp, out, cvb);
}

// Round 4
// 9737.840 us; speedup vs baseline: 2.1712x; 1.1844x over previous
//
#include <hip/hip_runtime.h>
#include <hip/hip_bf16.h>

// LSTM: B=64, D=32, H=512, T=1024. gates = [h,x] @ [W_hh;W_ih]^T + b_ih + b_hh
// Round 4: fence-free h exchange. h packed (bf16hi<<16|bf16lo) one dword/unit,
// moved with relaxed AGENT-scope atomics (SC1 write-through stores / bypass
// loads) -> coherent at Infinity Cache with ZERO buffer_wbl2/buffer_inv.
// Ordering: h stores -> __syncthreads (vmcnt0 retires write-through at L3)
// -> relaxed flag store. Consumer: poll flag (SC1) -> SC1 h loads.
// 128 blocks (4 batch-groups x 32 slices of 16 units), 256 thr (4 waves).
// W_hi in VGPRs, W_lo in LDS. Out projection via partials + k_reduce.

typedef unsigned short ushort_t;
typedef unsigned int   uint_t;
typedef unsigned long long u64_t;
typedef __attribute__((ext_vector_type(8))) short bf16x8;
typedef __attribute__((ext_vector_type(4))) float f32x4;

#define T_STEPS 1024
#define HID     512
#define KDIM    544   // 512 h + 32 x
#define NBLK    128   // 4 groups * 32 slices
#define NTHR    256

__device__ inline ushort_t f2bf(float x) {
    __hip_bfloat16 h = __float2bfloat16(x);
    return *(ushort_t*)&h;
}
__device__ inline float bf2f(ushort_t u) {
    __hip_bfloat16 h = *(__hip_bfloat16*)&u;
    return __bfloat162float(h);
}

__device__ inline f32x4 MFMA(bf16x8 a, bf16x8 b, f32x4 c) {
    return __builtin_amdgcn_mfma_f32_16x16x32_bf16(a, b, c, 0, 0, 0);
}

// is_tanh: tanh(v)=(1-e)/(1+e), e=2^(-2.885*v); sigmoid(v)=1/(1+e), e=2^(-1.4427*v)
__device__ inline float act_gate(float v, int is_tanh) {
    float vc = fminf(fmaxf(v, -43.f), 43.f);
    float kk = is_tanh ? -2.88539008f : -1.44269504f;
    float e  = __builtin_exp2f(vc * kk);
    float num = is_tanh ? (1.f - e) : 1.f;
    return num * __builtin_amdgcn_rcpf(1.f + e);
}

__device__ inline float sel4(int i, float a, float b, float c, float d) {
    return (i == 0) ? a : (i == 1) ? b : (i == 2) ? c : d;
}

// ---------- prep kernels ----------

__global__ void k_init(uint_t* flags, uint_t* hp) {
    int i = blockIdx.x * 256 + threadIdx.x;     // grid 512x256 = 131072
    flags[i] = 0;                                // 1024*128 u32 = exactly 131072
    if (i < 65536) hp[i] = 0;                    // packed h ring, both slots
}

__global__ void k_wcat(const float* __restrict__ wih, const float* __restrict__ whh,
                       ushort_t* __restrict__ wh, ushort_t* __restrict__ wl) {
    int r = blockIdx.x;                          // 2048 gate rows
    for (int k = threadIdx.x; k < KDIM; k += 256) {
        float w = (k < 512) ? whh[r * 512 + k] : wih[r * 32 + (k - 512)];
        ushort_t hh = f2bf(w);
        ushort_t ll = f2bf(w - bf2f(hh));
        wh[r * KDIM + k] = hh;
        wl[r * KDIM + k] = ll;
    }
}

// input (B=64, D=32, T=1024) fp32 -> xbuf[t][b][d] bf16 hi/lo
__global__ void k_xbuf(const float* __restrict__ in,
                       ushort_t* __restrict__ xh, ushort_t* __restrict__ xl) {
    __shared__ float tile[64][65];
    int bp = blockIdx.x >> 4;                    // batch pair 0..31
    int tt = blockIdx.x & 15;                    // t tile 0..15
    int t0 = tt * 64;
    int wv = threadIdx.x >> 6, l = threadIdx.x & 63;
    for (int r = wv * 16; r < wv * 16 + 16; r++) {
        int b = bp * 2 + (r >> 5), d = r & 31;
        tile[r][l] = in[(b * 32 + d) * 1024 + t0 + l];
    }
    __syncthreads();
    for (int i = 0; i < 16; i++) {
        int tl = wv * 16 + i;
        float v = tile[l][tl];
        ushort_t hh = f2bf(v);
        ushort_t ll = f2bf(v - bf2f(hh));
        int o = (t0 + tl) * 2048 + bp * 64 + l;  // = t*64*32 + b*32 + d
        xh[o] = hh;
        xl[o] = ll;
    }
}

// final: out[b][t] = conv_b + sum_s part[b][t][s]
__global__ void k_reduce(const float* __restrict__ part, float* __restrict__ out,
                         const float* __restrict__ cvb) {
    int idx = blockIdx.x * 256 + threadIdx.x;    // 65536 = (b,t) pairs
    const float* p = part + (size_t)idx * 32;
    float s = 0.f;
    #pragma unroll
    for (int k = 0; k < 8; k++) {
        f32x4 v = *(const f32x4*)(p + k * 4);
        s += (v[0] + v[1]) + (v[2] + v[3]);
    }
    out[idx] = s + cvb[0];
}

// ---------- main recurrent kernel ----------

__global__ __launch_bounds__(NTHR, 1) void k_lstm(
    const ushort_t* __restrict__ wh, const ushort_t* __restrict__ wlo,
    const ushort_t* __restrict__ xh, const ushort_t* __restrict__ xl,
    uint_t* hp, uint_t* flags,
    const float* __restrict__ bih, const float* __restrict__ bhh,
    const float* __restrict__ convw, float* __restrict__ part)
{
    const int tid = threadIdx.x;
    const int w   = tid >> 6;          // wave 0..3 (unit nibble)
    const int l   = tid & 63;
    const int g   = blockIdx.x >> 5;   // batch group 0..3
    const int s   = blockIdx.x & 31;   // hidden slice 0..31 (16 units each)
    const int n   = l & 15;            // B-tile row within wave
    const int q   = l >> 4;            // quad
    const int gtn = n >> 2;            // gate 0..3 (i,f,g,o)
    const int u   = n & 3;             // unit within wave
    const int j   = s * 16 + w * 4 + u;// hidden unit 0..511
    const int row = gtn * HID + j;     // gate row 0..2047
    const int b0  = g * 16;

    __shared__ ushort_t blo[64][552];  // W_lo slice, padded stride
    __shared__ float predsh[4][16];

    // stage W_lo to LDS: 64 rows x 544, 8-elem (16B) chunks
    for (int e = tid; e < 64 * 68; e += NTHR) {
        int rl = e / 68, ch = e - rl * 68;
        int ww = rl >> 4, nn = rl & 15;
        int gg = nn >> 2, uu = nn & 3;
        int rr = gg * HID + s * 16 + ww * 4 + uu;
        *(bf16x8*)&blo[rl][ch * 8] = *(const bf16x8*)(wlo + rr * KDIM + ch * 8);
    }

    // W_hi fragments in registers: 17 K-chunks
    bf16x8 Bh[17];
    #pragma unroll
    for (int c = 0; c < 17; c++)
        Bh[c] = *(const bf16x8*)(wh + row * KDIM + c * 32 + q * 8);

    const float bias = bih[row] + bhh[row];
    const float cw   = convw[j];
    float cst[4] = {0.f, 0.f, 0.f, 0.f};

    __syncthreads();
    const int rl16 = w * 16 + n;

    for (int t = 0; t < T_STEPS; t++) {
        bf16x8 Ah[17], Al[17];
        // x fragment: no dependence on flags -> prefetch into regs before poll
        {
            int xo = (t * 64 + b0 + n) * 32 + q * 8;
            Ah[16] = *(const bf16x8*)(xh + xo);
            Al[16] = *(const bf16x8*)(xl + xo);
        }

        if (t > 0) {
            if (w == 0) {
                const uint_t* my = flags + (t - 1) * 128 + g * 32 + (l & 31);
                for (;;) {
                    uint_t f = __hip_atomic_load(my, __ATOMIC_RELAXED,
                                                 __HIP_MEMORY_SCOPE_AGENT);
                    if (__all(f != 0)) break;
                }
            }
            __syncthreads();   // all waves held until group's step t-1 visible
        }

        // h fragments from ring slot t&1 (rows m=n), via SC1 bypass loads.
        // packed dword = (bf16hi<<16)|bf16lo per unit.
        {
            const uint_t* hrow = hp + (size_t)((((t & 1) * 4 + g) * 16 + n)) * HID;
            #pragma unroll
            for (int c = 0; c < 16; c++) {
                const u64_t* p = (const u64_t*)(hrow + c * 32 + q * 8);
                u64_t d0 = __hip_atomic_load(p + 0, __ATOMIC_RELAXED,
                                             __HIP_MEMORY_SCOPE_AGENT);
                u64_t d1 = __hip_atomic_load(p + 1, __ATOMIC_RELAXED,
                                             __HIP_MEMORY_SCOPE_AGENT);
                u64_t d2 = __hip_atomic_load(p + 2, __ATOMIC_RELAXED,
                                             __HIP_MEMORY_SCOPE_AGENT);
                u64_t d3 = __hip_atomic_load(p + 3, __ATOMIC_RELAXED,
                                             __HIP_MEMORY_SCOPE_AGENT);
                uint_t p0 = (uint_t)d0, p1 = (uint_t)(d0 >> 32);
                uint_t p2 = (uint_t)d1, p3 = (uint_t)(d1 >> 32);
                uint_t p4 = (uint_t)d2, p5 = (uint_t)(d2 >> 32);
                uint_t p6 = (uint_t)d3, p7 = (uint_t)(d3 >> 32);
                union { uint_t u[4]; bf16x8 v; } ah, al;
                ah.u[0] = __builtin_amdgcn_perm(p1, p0, 0x07060302u);
                ah.u[1] = __builtin_amdgcn_perm(p3, p2, 0x07060302u);
                ah.u[2] = __builtin_amdgcn_perm(p5, p4, 0x07060302u);
                ah.u[3] = __builtin_amdgcn_perm(p7, p6, 0x07060302u);
                al.u[0] = __builtin_amdgcn_perm(p1, p0, 0x05040100u);
                al.u[1] = __builtin_amdgcn_perm(p3, p2, 0x05040100u);
                al.u[2] = __builtin_amdgcn_perm(p5, p4, 0x05040100u);
                al.u[3] = __builtin_amdgcn_perm(p7, p6, 0x05040100u);
                Ah[c] = ah.v;
                Al[c] = al.v;
            }
        }

        f32x4 a0 = {0,0,0,0}, a1 = {0,0,0,0}, a2 = {0,0,0,0},
              a3 = {0,0,0,0}, a4 = {0,0,0,0}, a5 = {0,0,0,0};
        #pragma unroll
        for (int c = 0; c < 17; c++) {
            bf16x8 bl_ = *(const bf16x8*)&blo[rl16][c * 32 + q * 8];
            if (c & 1) {
                a1 = MFMA(Ah[c], Bh[c], a1);
                a3 = MFMA(Ah[c], bl_,   a3);
                a5 = MFMA(Al[c], Bh[c], a5);
            } else {
                a0 = MFMA(Ah[c], Bh[c], a0);
                a2 = MFMA(Ah[c], bl_,   a2);
                a4 = MFMA(Al[c], Bh[c], a4);
            }
        }
        f32x4 D = (a0 + a1) + (a2 + a3) + (a4 + a5);

        // epilogue: lane holds gate row n for batches m=q*4+r
        float hv[4], pr[4];
        #pragma unroll
        for (int r = 0; r < 4; r++) {
            float v   = D[r] + bias;
            float act = act_gate(v, gtn == 2);
            float v4  = __shfl_xor(act, 4);
            float v8  = __shfl_xor(act, 8);
            float v12 = __shfl_xor(v4, 8);
            // gate G lives at arr[gtn ^ G]; arr = {act, v4, v8, v12}
            float iv = sel4(gtn,     act, v4, v8, v12);
            float fv = sel4(gtn ^ 1, act, v4, v8, v12);
            float gv = sel4(gtn ^ 2, act, v4, v8, v12);
            float ov = sel4(gtn ^ 3, act, v4, v8, v12);
            float cc = fv * cst[r] + iv * gv;
            cst[r] = cc;
            float th = act_gate(cc, 1);
            float h  = ov * th;
            hv[r] = h;
            pr[r] = cw * h;
        }
        // write h_t packed to ring slot (t+1)&1 via SC1 write-through stores
        if (gtn == 0) {
            uint_t* dst = hp + (size_t)((((t + 1) & 1) * 4 + g) * 16) * HID;
            #pragma unroll
            for (int r = 0; r < 4; r++) {
                int m2 = q * 4 + r;
                float h = hv[r];
                ushort_t hh = f2bf(h);
                ushort_t ll = f2bf(h - bf2f(hh));
                uint_t pk = ((uint_t)hh << 16) | (uint_t)ll;
                __hip_atomic_store(dst + m2 * HID + j, pk, __ATOMIC_RELAXED,
                                   __HIP_MEMORY_SCOPE_AGENT);
            }
        }
        // projection partial over this wave's 4 units (lane bits 0..1)
        #pragma unroll
        for (int r = 0; r < 4; r++) {
            pr[r] += __shfl_xor(pr[r], 1);
            pr[r] += __shfl_xor(pr[r], 2);
        }
        if (n == 0) {
            #pragma unroll
            for (int r = 0; r < 4; r++) predsh[w][q * 4 + r] = pr[r];
        }
        __syncthreads();   // vmcnt(0) drain: write-through h stores at L3
        if (tid == 0)
            __hip_atomic_store(flags + t * 128 + g * 32 + s, 1u,
                               __ATOMIC_RELAXED, __HIP_MEMORY_SCOPE_AGENT);
        if (tid < 16) {    // projection partial -> global, reduced after kernel
            float tot = (predsh[0][tid] + predsh[1][tid]) +
                        (predsh[2][tid] + predsh[3][tid]);
            __builtin_nontemporal_store(tot,
                part + (size_t)((b0 + tid) * 1024 + t) * 32 + s);
        }
        // next iteration's predsh writes are gated by its poll+__syncthreads,
        // which orders them after this iteration's predsh reads.
    }
}

extern "C" void kernel_launch(void* const* d_in, const int* in_sizes, int n_in,
                              void* d_out, int out_size, void* d_ws, size_t ws_size,
                              hipStream_t stream) {
    const float* in  = (const float*)d_in[0];
    const float* Wih = (const float*)d_in[1];
    const float* Whh = (const float*)d_in[2];
    const float* bih = (const float*)d_in[3];
    const float* bhh = (const float*)d_in[4];
    const float* cvw = (const float*)d_in[5];
    const float* cvb = (const float*)d_in[6];
    float* out = (float*)d_out;

    char* ws = (char*)d_ws;
    ushort_t* wh = (ushort_t*)ws; ws += (size_t)2048 * KDIM * 2;      // 2,228,224
    ushort_t* wl = (ushort_t*)ws; ws += (size_t)2048 * KDIM * 2;
    ushort_t* xh = (ushort_t*)ws; ws += (size_t)1024 * 64 * 32 * 2;   // 4,194,304
    ushort_t* xl = (ushort_t*)ws; ws += (size_t)1024 * 64 * 32 * 2;
    uint_t*   hp = (uint_t*)ws;   ws += (size_t)2 * 64 * HID * 4;     // 262,144
    uint_t*   fl = (uint_t*)ws;   ws += (size_t)T_STEPS * 128 * 4;    // 524,288
    float*    pp = (float*)ws;    ws += (size_t)64 * 1024 * 32 * 4;   // 8,388,608
    // total ~22.3 MB of ws

    k_init<<<512, 256, 0, stream>>>(fl, hp);
    k_wcat<<<2048, 256, 0, stream>>>(Wih, Whh, wh, wl);
    k_xbuf<<<512, 256, 0, stream>>>(in, xh, xl);
    k_lstm<<<NBLK, NTHR, 0, stream>>>(wh, wl, xh, xl, hp, fl,
                                      bih, bhh, cvw, pp);
    k_reduce<<<256, 256, 0, stream>>>(pp, out, cvb);
}